// Round 10
// baseline (432.772 us; speedup 1.0000x reference)
//
#include <hip/hip_runtime.h>
#include <cmath>

#define HH 512
#define WW 512
#define BB 8
#define WP (WW + 4)    // padded row width (2-px halo each side)
#define HP (HH + 4)    // padded rows (2 zero-rows top/bottom)

#define PROWS 520      // x-plane rows: 512 + 4 top + 4 bottom
#define PCOLS 528      // x-plane cols: 512 + 4 left + 12 right (kx pad to 16)
#define PT ((size_t)BB * PROWS * PCOLS)

typedef int v4i __attribute__((ext_vector_type(4)));
typedef int v16i __attribute__((ext_vector_type(16)));
typedef float v4f __attribute__((ext_vector_type(4)));
typedef _Float16 v8h __attribute__((ext_vector_type(8)));

#if defined(__has_builtin)
#if __has_builtin(__builtin_amdgcn_sdot4)
#define DOT4(a, b, c) __builtin_amdgcn_sdot4((a), (b), (c), false)
#endif
#endif
#ifndef DOT4
static __device__ __forceinline__ int dot4_fb(int a, int b, int c) {
  c += ((a << 24) >> 24) * ((b << 24) >> 24);
  c += ((a << 16) >> 24) * ((b << 16) >> 24);
  c += ((a << 8) >> 24) * ((b << 8) >> 24);
  c += (a >> 24) * (b >> 24);
  return c;
}
#define DOT4(a, b, c) dot4_fb((a), (b), (c))
#endif

// -------- workspace layout --------
static constexpr size_t SCALES_OFF = 0;        // float[3]
static constexpr size_t CORRF_OFF  = 64;       // int[32]
static constexpr size_t QA_OFF     = 256;      // float[2]: A1, A2
static constexpr size_t FS3_OFF    = 512;      // int[1]
static constexpr size_t QW1_OFF    = 1024;     // float[64*81] (ends 21760)
static constexpr size_t B1Q_OFF    = 21760;    // float[64]: b1/step1 - 128
static constexpr size_t B2Q_OFF    = 22016;    // float[32]: b2/step2 - 128
static constexpr size_t W1FRAG_OFF = 24576;    // f16[9*4*64*8]
static constexpr size_t W2S_OFF    = 65536;    // i8[25*2*64*16]  (32x32 A-frag layout)
static constexpr size_t W3P_OFF    = 131072;   // i8[25*32]
static constexpr size_t H1_OFF     = (size_t)1 << 20;
static constexpr size_t H1_SZ      = (size_t)BB * HP * WP * 64;
static constexpr size_t H2_OFF     = H1_OFF + H1_SZ;
static constexpr size_t H2_SZ      = (size_t)BB * HP * WP * 32;
static constexpr size_t WS_NEED    = H2_OFF + H2_SZ;
// x-planes (4*PT f16 = 17.6 MB) live in the h2p region until conv2 runs.

// -------- weight quantization --------
__global__ void quant_weights_k(const float* __restrict__ w1,
                                const float* __restrict__ w2,
                                const float* __restrict__ w3,
                                float* __restrict__ scales,
                                float* __restrict__ qw1,
                                signed char* __restrict__ w2s,
                                signed char* __restrict__ w3p) {
  const int t = blockIdx.x;
  const float* src = (t == 0) ? w1 : (t == 1) ? w2 : w3;
  const int n = (t == 0) ? 64 * 81 : (t == 1) ? 32 * 64 * 25 : 32 * 25;
  __shared__ float red[256];
  float m = 0.0f;
  for (int i = threadIdx.x; i < n; i += 256) m = fmaxf(m, fabsf(src[i]));
  red[threadIdx.x] = m;
  __syncthreads();
  for (int s = 128; s > 0; s >>= 1) {
    if ((int)threadIdx.x < s) red[threadIdx.x] = fmaxf(red[threadIdx.x], red[threadIdx.x + s]);
    __syncthreads();
  }
  const float scale = red[0] / 127.0f;
  if (threadIdx.x == 0) scales[t] = scale;
  for (int i = threadIdx.x; i < n; i += 256) {
    float q = rintf(src[i] / scale);
    q = fminf(fmaxf(q, -127.0f), 127.0f);
    if (t == 0) {
      qw1[i] = q;
    } else if (t == 1) {
      // w2 (oc=32, ic=64, 5, 5) -> A-frag for mfma 32x32x32:
      // [tap][half=ic>>5][lane = ((ic>>4)&1)*32 + oc][j = ic&15]
      const int oc = i / 1600;
      const int r = i - oc * 1600;
      const int ic = r / 25, tap = r - ic * 25;
      const int addr = (tap * 2 + (ic >> 5)) * 1024 + ((ic >> 4) & 1) * 512
                     + oc * 16 + (ic & 15);
      w2s[addr] = (signed char)(int)q;
    } else {
      const int ic = i / 25, tap = i - ic * 25;
      w3p[tap * 32 + ic] = (signed char)(int)q;
    }
  }
}

// -------- prep: corrf / fs3 / quant-fold params / conv1 B-fragments --------
__global__ void prep_k(const signed char* __restrict__ w2s,
                       const signed char* __restrict__ w3p,
                       const float* __restrict__ qw1,
                       const float* __restrict__ b1,
                       const float* __restrict__ b2,
                       const float* __restrict__ s1,
                       const float* __restrict__ s2,
                       const float* __restrict__ scales,
                       int* __restrict__ corrf, int* __restrict__ fs3,
                       unsigned short* __restrict__ w1frag,
                       float* __restrict__ qA,
                       float* __restrict__ b1q,
                       float* __restrict__ b2q) {
  const int tid = threadIdx.x;
  __shared__ int red3[32];
  // corrf[oc] = signed byte-sum over taps/ic (dwords chunk*128 + oc*4..+3)
  {
    const int oc = tid >> 3, part = tid & 7;
    const unsigned int* wd = (const unsigned int*)w2s;
    int s = 0;
    for (int chunk = part; chunk < 100; chunk += 8) {
      const int base = chunk * 128 + oc * 4;
      #pragma unroll
      for (int j = 0; j < 4; ++j) s = DOT4((int)wd[base + j], 0x01010101, s);
    }
    s += __shfl_xor(s, 1);
    s += __shfl_xor(s, 2);
    s += __shfl_xor(s, 4);
    if (part == 0) corrf[oc] = s;
  }
  // fs3 = byte-sum of all w3p
  if (tid < 32) {
    int s = 0;
    if (tid < 25) {
      const unsigned int* wd = (const unsigned int*)w3p;
      #pragma unroll
      for (int j = 0; j < 8; ++j) s = DOT4((int)wd[tid * 8 + j], 0x01010101, s);
    }
    red3[tid] = s;
  }
  __syncthreads();
  if (tid == 0) {
    int s = 0;
    #pragma unroll
    for (int j = 0; j < 32; ++j) s += red3[j];
    fs3[0] = s;
  }
  // quant-fold params
  {
    const float step1 = s1[0] / 255.0f;
    const float step2 = s2[0] / 255.0f;
    if (tid < 64) {
      b1q[tid] = b1[tid] / step1 - 128.0f;
    } else if (tid < 96) {
      b2q[tid - 64] = b2[tid - 64] / step2 - 128.0f;
    } else if (tid == 96) {
      qA[0] = scales[0] / step1;                    // conv1: acc*A1
      qA[1] = (step1 * scales[1]) / step2;          // conv2: acc*A2
    }
  }
  // conv1 B-frags
  for (int i = tid; i < 18432; i += 256) {
    const int e = i & 7, lidx = (i >> 3) & 63, nn = (i >> 9) & 3, j = i >> 11;
    const int t = j * 32 + (lidx >> 4) * 8 + e;
    const int term = (t >= 144) ? 1 : 0;
    const int rem = t - term * 144;
    const int ky = rem >> 4, kx = rem & 15;
    const int oc = nn * 16 + (lidx & 15);
    float v = 0.0f;
    if (kx < 9) v = qw1[oc * 81 + ky * 9 + kx];
    if (term) v *= (1.0f / 4096.0f);
    const _Float16 hv = (_Float16)v;
    w1frag[i] = __builtin_bit_cast(unsigned short, hv);
  }
}

// -------- prep x-planes: f16 hi/lo split, zero-padded, parity-duplicated --------
__global__ __launch_bounds__(256) void prep_x_k(const float* __restrict__ x,
                                                unsigned short* __restrict__ planes) {
  const size_t i = (size_t)blockIdx.x * 256 + threadIdx.x;
  if (i >= PT) return;
  const int col = (int)(i % PCOLS);
  const size_t t = i / PCOLS;
  const int row = (int)(t % PROWS);
  const int b = (int)(t / PROWS);
  const float* xb = x + (size_t)b * HH * WW;
  const int xr = row - 4;
  float v0 = 0.0f, v1 = 0.0f;
  if (xr >= 0 && xr < HH) {
    const int c0 = col - 4, c1 = col - 3;
    if (c0 >= 0 && c0 < WW) v0 = xb[(size_t)xr * WW + c0];
    if (c1 >= 0 && c1 < WW) v1 = xb[(size_t)xr * WW + c1];
  }
  const _Float16 h0 = (_Float16)v0;
  const _Float16 l0 = (_Float16)((v0 - (float)h0) * 4096.0f);
  const _Float16 h1 = (_Float16)v1;
  const _Float16 l1 = (_Float16)((v1 - (float)h1) * 4096.0f);
  planes[i]          = __builtin_bit_cast(unsigned short, h0);
  planes[PT + i]     = __builtin_bit_cast(unsigned short, l0);
  planes[2 * PT + i] = __builtin_bit_cast(unsigned short, h1);
  planes[3 * PT + i] = __builtin_bit_cast(unsigned short, l1);
}

// -------- fill borders of h1p/h2p with 0x80 (biased zero) --------
__global__ void fill_k(unsigned char* __restrict__ h1p, unsigned char* __restrict__ h2p) {
  const int idx = blockIdx.x * 256 + threadIdx.x;
  const uint4 v = make_uint4(0x80808080u, 0x80808080u, 0x80808080u, 0x80808080u);
  if (idx < 66048) {
    const int q = idx & 3; const int u = idx >> 2;
    const int pxi = u % WP; const int rr = u / WP;
    const int bb = rr >> 2, sel = rr & 3;
    const int row = (sel < 2) ? sel : 512 + sel;
    *(uint4*)(h1p + (((size_t)bb * HP + row) * WP + pxi) * 64 + q * 16) = v;
  } else if (idx < 131584) {
    const int e = idx - 66048; const int q = e & 3; int u = e >> 2;
    const int c = u & 3; u >>= 2;
    const int row = 2 + (u & 511); const int bb = u >> 9;
    const int col = (c < 2) ? c : 512 + c;
    *(uint4*)(h1p + (((size_t)bb * HP + row) * WP + col) * 64 + q * 16) = v;
  } else if (idx < 164608) {
    const int e = idx - 131584; const int q = e & 1; const int u = e >> 1;
    const int pxi = u % WP; const int rr = u / WP;
    const int bb = rr >> 2, sel = rr & 3;
    const int row = (sel < 2) ? sel : 512 + sel;
    *(uint4*)(h2p + (((size_t)bb * HP + row) * WP + pxi) * 32 + q * 16) = v;
  } else {
    const int e = idx - 164608; const int q = e & 1; int u = e >> 1;
    const int c = u & 3; u >>= 2;
    const int row = 2 + (u & 511); const int bb = u >> 9;
    const int col = (c < 2) ? c : 512 + c;
    *(uint4*)(h2p + (((size_t)bb * HP + row) * WP + col) * 32 + q * 16) = v;
  }
}

// -------- conv1: f16-split MFMA, XCD-chunked rows (planes L2-resident), j-prefetch ---
__global__ __launch_bounds__(512) void conv1_k(
    const unsigned short* __restrict__ planes,
    const unsigned short* __restrict__ w1frag,
    const float* __restrict__ qA,
    const float* __restrict__ b1q,
    unsigned char* __restrict__ h1p) {
  __shared__ alignas(16) unsigned short wf[18432];
  for (int i = threadIdx.x; i < 2304; i += 512)
    ((int4*)wf)[i] = ((const int4*)w1frag)[i];
  __syncthreads();

  // XCD-chunked swizzle: 4096 blocks, 8 XCDs, 512 blocks/XCD -> XCD k owns image k.
  // Its 4 planes (2.2 MB) become L2-resident; 9x ky row-reuse = L2 hits.
  const int wg = (blockIdx.x & 7) * 512 + (blockIdx.x >> 3);
  const int y = wg & (HH - 1);
  const int b = wg >> 9;
  const int l = threadIdx.x & 63;
  const int wv = threadIdx.x >> 6;
  const int pxw = wv * 64;
  const int r = l & 15, kb = l >> 4;

  const unsigned short* pb = planes + (size_t)(r & 1) * (2 * PT)
                           + ((size_t)b * PROWS + y) * PCOLS + (pxw + (r & ~1));
  int offs[9];
  #pragma unroll
  for (int j = 0; j < 9; ++j) {
    const int t0 = j * 32 + kb * 8;
    const int term = (t0 >= 144) ? 1 : 0;
    const int rem = t0 - term * 144;
    offs[j] = term * (int)PT + (rem >> 4) * PCOLS + (rem & 8);
  }

  v4f acc[4][4];   // [p = px-tile][o = oc-tile]
  #pragma unroll
  for (int p = 0; p < 4; ++p)
    #pragma unroll
    for (int o = 0; o < 4; ++o) acc[p][o] = (v4f){0.f, 0.f, 0.f, 0.f};

  // ping-pong prefetch: issue j+1's A-loads before j's MFMAs
  v8h av[2][4];
  #pragma unroll
  for (int p = 0; p < 4; ++p) {
    uint4 tv;
    __builtin_memcpy(&tv, __builtin_assume_aligned((const void*)(pb + offs[0] + p * 16), 4), 16);
    av[0][p] = __builtin_bit_cast(v8h, tv);
  }
  #pragma unroll
  for (int j = 0; j < 9; ++j) {
    const int cur = j & 1, nxt = cur ^ 1;
    if (j < 8) {
      #pragma unroll
      for (int p = 0; p < 4; ++p) {
        uint4 tv;
        __builtin_memcpy(&tv,
            __builtin_assume_aligned((const void*)(pb + offs[j + 1] + p * 16), 4), 16);
        av[nxt][p] = __builtin_bit_cast(v8h, tv);
      }
    }
    #pragma unroll
    for (int o = 0; o < 4; ++o) {
      const v8h bw = *(const v8h*)(wf + ((size_t)(j * 4 + o) * 64 + l) * 8);
      #pragma unroll
      for (int p = 0; p < 4; ++p)
        acc[p][o] = __builtin_amdgcn_mfma_f32_16x16x32_f16(bw, av[cur][p], acc[p][o], 0, 0, 0);
    }
  }

  const float A1 = qA[0];
  unsigned int* ob = (unsigned int*)(h1p
      + (((size_t)b * HP + y + 2) * WP + 2 + pxw + r) * 64 + kb * 4);
  #pragma unroll
  for (int o = 0; o < 4; ++o) {
    const v4f bq = *(const v4f*)(b1q + o * 16 + kb * 4);
    #pragma unroll
    for (int p = 0; p < 4; ++p) {
      unsigned int dw = 0;
      #pragma unroll
      for (int reg = 0; reg < 4; ++reg) {
        const float t = acc[p][o][reg] * A1 + bq[reg];
        int qi = (int)rintf(t);
        qi = qi < -128 ? -128 : (qi > 127 ? 127 : qi);
        dw |= ((unsigned int)qi & 0xFFu) << (8 * reg);
      }
      ob[p * 256 + o * 4] = dw;
    }
  }
}

// -------- conv2: mfma_i32_32x32x32_i8, fma-folded quant epilogue ------
__global__ __launch_bounds__(256) void conv2_k(
    const unsigned char* __restrict__ h1p,
    const int4* __restrict__ w2s,
    const int* __restrict__ corrf,
    const float* __restrict__ qA,
    const float* __restrict__ b2q,
    unsigned char* __restrict__ h2p) {
  __shared__ alignas(16) signed char wlds[51200];
  __shared__ alignas(16) int clds[32];
  {
    int4* dst = (int4*)wlds;
    for (int i = threadIdx.x; i < 3200; i += 256) dst[i] = w2s[i];
    if (threadIdx.x < 32) clds[threadIdx.x] = corrf[threadIdx.x];
  }
  __syncthreads();

  const int l = threadIdx.x & 63;
  const int wv = threadIdx.x >> 6;
  const int pl = l & 31;          // pixel lane
  const int hi = l >> 5;          // k-chunk selector
  const int y = blockIdx.y * 16 + wv * 4;
  const int b = blockIdx.z;
  const int xw = blockIdx.x * 32;

  v16i acc[4];
  #pragma unroll
  for (int t = 0; t < 4; ++t)
    #pragma unroll
    for (int e = 0; e < 16; ++e) acc[t][e] = 0;

  const size_t rstride = (size_t)WP * 64;
  const unsigned char* abase = h1p + (((size_t)b * HP + y) * WP + xw + pl) * 64 + hi * 16;
  const signed char* wbase = wlds + l * 16;

  #pragma unroll
  for (int kx = 0; kx < 5; ++kx) {
    v4i a[8][2];
    #pragma unroll
    for (int row = 0; row < 8; ++row) {
      a[row][0] = *(const v4i*)(abase + kx * 64 + row * rstride);
      a[row][1] = *(const v4i*)(abase + kx * 64 + row * rstride + 32);
    }
    #pragma unroll
    for (int ky = 0; ky < 5; ++ky) {
      #pragma unroll
      for (int h = 0; h < 2; ++h) {
        const v4i wfr = *(const v4i*)(wbase + ((ky * 5 + kx) * 2 + h) * 1024);
        #pragma unroll
        for (int t = 0; t < 4; ++t)
          acc[t] = __builtin_amdgcn_mfma_i32_32x32x32_i8(wfr, a[ky + t][h], acc[t], 0, 0, 0);
      }
    }
  }

  const float A2 = qA[1];
  #pragma unroll
  for (int t = 0; t < 4; ++t) {
    unsigned char* ob = h2p + (((size_t)b * HP + y + t + 2) * WP + xw + 2 + pl) * 32 + hi * 4;
    #pragma unroll
    for (int g = 0; g < 4; ++g) {
      const int ocb = g * 8 + hi * 4;
      const v4f bq = *(const v4f*)(b2q + ocb);
      const v4i cv = *(const v4i*)(clds + ocb);
      unsigned int dw = 0;
      #pragma unroll
      for (int q = 0; q < 4; ++q) {
        const int tot = acc[t][g * 4 + q] + cv[q] * 128;
        const float v = (float)tot * A2 + bq[q];
        int qi = (int)rintf(v);
        qi = qi < -128 ? -128 : (qi > 127 ? 127 : qi);
        dw |= ((unsigned int)qi & 0xFFu) << (8 * q);
      }
      *(unsigned int*)(ob + g * 8) = dw;
    }
  }
}

// -------- conv3: NHWC, vectorized 16B row loads + static-indexed dot4 (exact) ------
__global__ __launch_bounds__(256) void conv3_k(
    const unsigned char* __restrict__ h2p,
    const signed char* __restrict__ w3p,
    const int* __restrict__ fs3,
    const float* __restrict__ b3,
    const float* __restrict__ scales,
    const float* __restrict__ s2, const float* __restrict__ s3,
    float* __restrict__ out) {
  const int p  = blockIdx.x * 256 + threadIdx.x;
  const int px = p & (WW - 1);
  const int py = (p >> 9) & (HH - 1);
  const int bz = p >> 18;

  const int* wq = (const int*)w3p;   // [tap][8 dwords]
  const unsigned char* base = h2p + (((size_t)bz * HP + py) * WP + px) * 32;

  int acc = 0;
  #pragma unroll
  for (int ky = 0; ky < 5; ++ky) {
    const v4i* rp = (const v4i*)(base + (size_t)ky * WP * 32);
    v4i c[10];
    #pragma unroll
    for (int g = 0; g < 10; ++g) c[g] = rp[g];
    const int* wrow = wq + ky * 40;
    #pragma unroll
    for (int kx = 0; kx < 5; ++kx) {
      #pragma unroll
      for (int g = 0; g < 8; ++g) {
        const int idx = kx * 8 + g;
        acc = DOT4(c[idx >> 2][idx & 3], wrow[idx], acc);
      }
    }
  }

  const int tot = acc + fs3[0] * 128;
  const float step2 = s2[0] / 255.0f;
  const float sc3 = s3[0], step3 = sc3 / 255.0f;
  const float y = (float)tot * (step2 * scales[2]) + b3[0];
  const float c = fminf(fmaxf(y, 0.0f), sc3);
  float q = rintf(c / step3);
  q = fminf(fmaxf(q, 0.0f), 255.0f);
  out[p] = q * step3;
}

extern "C" void kernel_launch(void* const* d_in, const int* in_sizes, int n_in,
                              void* d_out, int out_size, void* d_ws, size_t ws_size,
                              hipStream_t stream) {
  const float* x  = (const float*)d_in[0];
  const float* w1 = (const float*)d_in[1];
  const float* b1 = (const float*)d_in[2];
  const float* w2 = (const float*)d_in[3];
  const float* b2 = (const float*)d_in[4];
  const float* w3 = (const float*)d_in[5];
  const float* b3 = (const float*)d_in[6];
  const float* s1 = (const float*)d_in[7];
  const float* s2 = (const float*)d_in[8];
  const float* s3 = (const float*)d_in[9];

  if (ws_size < WS_NEED) return;

  char* ws = (char*)d_ws;
  float*          scales  = (float*)(ws + SCALES_OFF);
  int*            corrf   = (int*)(ws + CORRF_OFF);
  float*          qA      = (float*)(ws + QA_OFF);
  int*            fs3     = (int*)(ws + FS3_OFF);
  float*          qw1     = (float*)(ws + QW1_OFF);
  float*          b1q     = (float*)(ws + B1Q_OFF);
  float*          b2q     = (float*)(ws + B2Q_OFF);
  unsigned short* w1frag  = (unsigned short*)(ws + W1FRAG_OFF);
  signed char*    w2s     = (signed char*)(ws + W2S_OFF);
  signed char*    w3p     = (signed char*)(ws + W3P_OFF);
  unsigned char*  h1p     = (unsigned char*)(ws + H1_OFF);
  unsigned char*  h2p     = (unsigned char*)(ws + H2_OFF);
  unsigned short* planes  = (unsigned short*)(ws + H2_OFF);  // overlaps h2p until conv2

  quant_weights_k<<<3, 256, 0, stream>>>(w1, w2, w3, scales, qw1, w2s, w3p);
  prep_k<<<1, 256, 0, stream>>>(w2s, w3p, qw1, b1, b2, s1, s2, scales,
                                corrf, fs3, w1frag, qA, b1q, b2q);
  prep_x_k<<<(int)(PT / 256), 256, 0, stream>>>(x, planes);

  conv1_k<<<BB * HH, 512, 0, stream>>>(planes, w1frag, qA, b1q, h1p);
  fill_k<<<771, 256, 0, stream>>>(h1p, h2p);   // after conv1 (h2p region held planes)

  dim3 g2(16, 32, BB);
  conv2_k<<<g2, 256, 0, stream>>>(h1p, (const int4*)w2s, corrf, qA, b2q, h2p);

  const int npix = BB * HH * WW;
  conv3_k<<<npix / 256, 256, 0, stream>>>(h2p, w3p, fs3, b3, scales, s2, s3, (float*)d_out);
}

// Round 11
// 430.083 us; speedup vs baseline: 1.0063x; 1.0063x over previous
//
#include <hip/hip_runtime.h>
#include <cmath>

#define HH 512
#define WW 512
#define BB 8
#define WP (WW + 4)    // padded row width (2-px halo each side)
#define HP (HH + 4)    // padded rows (2 zero-rows top/bottom)

#define PROWS 520      // x-plane rows: 512 + 4 top + 4 bottom
#define PCOLS 528      // x-plane cols: 512 + 4 left + 12 right (kx pad to 16)
#define PT ((size_t)BB * PROWS * PCOLS)

typedef int v4i __attribute__((ext_vector_type(4)));
typedef int v16i __attribute__((ext_vector_type(16)));
typedef float v4f __attribute__((ext_vector_type(4)));
typedef _Float16 v8h __attribute__((ext_vector_type(8)));

#if defined(__has_builtin)
#if __has_builtin(__builtin_amdgcn_sdot4)
#define DOT4(a, b, c) __builtin_amdgcn_sdot4((a), (b), (c), false)
#endif
#endif
#ifndef DOT4
static __device__ __forceinline__ int dot4_fb(int a, int b, int c) {
  c += ((a << 24) >> 24) * ((b << 24) >> 24);
  c += ((a << 16) >> 24) * ((b << 16) >> 24);
  c += ((a << 8) >> 24) * ((b << 8) >> 24);
  c += (a >> 24) * (b >> 24);
  return c;
}
#define DOT4(a, b, c) dot4_fb((a), (b), (c))
#endif

// -------- workspace layout --------
static constexpr size_t SCALES_OFF = 0;        // float[3]
static constexpr size_t CORRF_OFF  = 64;       // int[32]
static constexpr size_t QA_OFF     = 256;      // float[2]: A1, A2
static constexpr size_t FS3_OFF    = 512;      // int[1]
static constexpr size_t QW1_OFF    = 1024;     // float[64*81] (ends 21760)
static constexpr size_t B1Q_OFF    = 21760;    // float[64]: b1/step1 - 128
static constexpr size_t B2Q_OFF    = 22016;    // float[32]: b2/step2 - 128
static constexpr size_t W1FRAG_OFF = 24576;    // f16[9*4*64*8]
static constexpr size_t W2S_OFF    = 65536;    // i8[25*2*64*16]  (32x32 A-frag layout)
static constexpr size_t W3P_OFF    = 131072;   // i8[25*32]
static constexpr size_t H1_OFF     = (size_t)1 << 20;
static constexpr size_t H1_SZ      = (size_t)BB * HP * WP * 64;
static constexpr size_t H2_OFF     = H1_OFF + H1_SZ;
static constexpr size_t H2_SZ      = (size_t)BB * HP * WP * 32;
static constexpr size_t WS_NEED    = H2_OFF + H2_SZ;
// x-planes (4*PT f16 = 17.6 MB) live in the h2p region until conv2 runs.

// -------- weight quantization --------
__global__ void quant_weights_k(const float* __restrict__ w1,
                                const float* __restrict__ w2,
                                const float* __restrict__ w3,
                                float* __restrict__ scales,
                                float* __restrict__ qw1,
                                signed char* __restrict__ w2s,
                                signed char* __restrict__ w3p) {
  const int t = blockIdx.x;
  const float* src = (t == 0) ? w1 : (t == 1) ? w2 : w3;
  const int n = (t == 0) ? 64 * 81 : (t == 1) ? 32 * 64 * 25 : 32 * 25;
  __shared__ float red[256];
  float m = 0.0f;
  for (int i = threadIdx.x; i < n; i += 256) m = fmaxf(m, fabsf(src[i]));
  red[threadIdx.x] = m;
  __syncthreads();
  for (int s = 128; s > 0; s >>= 1) {
    if ((int)threadIdx.x < s) red[threadIdx.x] = fmaxf(red[threadIdx.x], red[threadIdx.x + s]);
    __syncthreads();
  }
  const float scale = red[0] / 127.0f;
  if (threadIdx.x == 0) scales[t] = scale;
  for (int i = threadIdx.x; i < n; i += 256) {
    float q = rintf(src[i] / scale);
    q = fminf(fmaxf(q, -127.0f), 127.0f);
    if (t == 0) {
      qw1[i] = q;
    } else if (t == 1) {
      // w2 (oc=32, ic=64, 5, 5) -> A-frag for mfma 32x32x32:
      // [tap][half=ic>>5][lane = ((ic>>4)&1)*32 + oc][j = ic&15]
      const int oc = i / 1600;
      const int r = i - oc * 1600;
      const int ic = r / 25, tap = r - ic * 25;
      const int addr = (tap * 2 + (ic >> 5)) * 1024 + ((ic >> 4) & 1) * 512
                     + oc * 16 + (ic & 15);
      w2s[addr] = (signed char)(int)q;
    } else {
      const int ic = i / 25, tap = i - ic * 25;
      w3p[tap * 32 + ic] = (signed char)(int)q;
    }
  }
}

// -------- prep: corrf / fs3 / quant-fold params / conv1 B-fragments --------
__global__ void prep_k(const signed char* __restrict__ w2s,
                       const signed char* __restrict__ w3p,
                       const float* __restrict__ qw1,
                       const float* __restrict__ b1,
                       const float* __restrict__ b2,
                       const float* __restrict__ s1,
                       const float* __restrict__ s2,
                       const float* __restrict__ scales,
                       int* __restrict__ corrf, int* __restrict__ fs3,
                       unsigned short* __restrict__ w1frag,
                       float* __restrict__ qA,
                       float* __restrict__ b1q,
                       float* __restrict__ b2q) {
  const int tid = threadIdx.x;
  __shared__ int red3[32];
  // corrf[oc] = signed byte-sum over taps/ic (dwords chunk*128 + oc*4..+3)
  {
    const int oc = tid >> 3, part = tid & 7;
    const unsigned int* wd = (const unsigned int*)w2s;
    int s = 0;
    for (int chunk = part; chunk < 100; chunk += 8) {
      const int base = chunk * 128 + oc * 4;
      #pragma unroll
      for (int j = 0; j < 4; ++j) s = DOT4((int)wd[base + j], 0x01010101, s);
    }
    s += __shfl_xor(s, 1);
    s += __shfl_xor(s, 2);
    s += __shfl_xor(s, 4);
    if (part == 0) corrf[oc] = s;
  }
  // fs3 = byte-sum of all w3p
  if (tid < 32) {
    int s = 0;
    if (tid < 25) {
      const unsigned int* wd = (const unsigned int*)w3p;
      #pragma unroll
      for (int j = 0; j < 8; ++j) s = DOT4((int)wd[tid * 8 + j], 0x01010101, s);
    }
    red3[tid] = s;
  }
  __syncthreads();
  if (tid == 0) {
    int s = 0;
    #pragma unroll
    for (int j = 0; j < 32; ++j) s += red3[j];
    fs3[0] = s;
  }
  // quant-fold params
  {
    const float step1 = s1[0] / 255.0f;
    const float step2 = s2[0] / 255.0f;
    if (tid < 64) {
      b1q[tid] = b1[tid] / step1 - 128.0f;
    } else if (tid < 96) {
      b2q[tid - 64] = b2[tid - 64] / step2 - 128.0f;
    } else if (tid == 96) {
      qA[0] = scales[0] / step1;                    // conv1: acc*A1
      qA[1] = (step1 * scales[1]) / step2;          // conv2: acc*A2
    }
  }
  // conv1 B-frags
  for (int i = tid; i < 18432; i += 256) {
    const int e = i & 7, lidx = (i >> 3) & 63, nn = (i >> 9) & 3, j = i >> 11;
    const int t = j * 32 + (lidx >> 4) * 8 + e;
    const int term = (t >= 144) ? 1 : 0;
    const int rem = t - term * 144;
    const int ky = rem >> 4, kx = rem & 15;
    const int oc = nn * 16 + (lidx & 15);
    float v = 0.0f;
    if (kx < 9) v = qw1[oc * 81 + ky * 9 + kx];
    if (term) v *= (1.0f / 4096.0f);
    const _Float16 hv = (_Float16)v;
    w1frag[i] = __builtin_bit_cast(unsigned short, hv);
  }
}

// -------- prep x-planes: f16 hi/lo split, zero-padded, parity-duplicated --------
__global__ __launch_bounds__(256) void prep_x_k(const float* __restrict__ x,
                                                unsigned short* __restrict__ planes) {
  const size_t i = (size_t)blockIdx.x * 256 + threadIdx.x;
  if (i >= PT) return;
  const int col = (int)(i % PCOLS);
  const size_t t = i / PCOLS;
  const int row = (int)(t % PROWS);
  const int b = (int)(t / PROWS);
  const float* xb = x + (size_t)b * HH * WW;
  const int xr = row - 4;
  float v0 = 0.0f, v1 = 0.0f;
  if (xr >= 0 && xr < HH) {
    const int c0 = col - 4, c1 = col - 3;
    if (c0 >= 0 && c0 < WW) v0 = xb[(size_t)xr * WW + c0];
    if (c1 >= 0 && c1 < WW) v1 = xb[(size_t)xr * WW + c1];
  }
  const _Float16 h0 = (_Float16)v0;
  const _Float16 l0 = (_Float16)((v0 - (float)h0) * 4096.0f);
  const _Float16 h1 = (_Float16)v1;
  const _Float16 l1 = (_Float16)((v1 - (float)h1) * 4096.0f);
  planes[i]          = __builtin_bit_cast(unsigned short, h0);
  planes[PT + i]     = __builtin_bit_cast(unsigned short, l0);
  planes[2 * PT + i] = __builtin_bit_cast(unsigned short, h1);
  planes[3 * PT + i] = __builtin_bit_cast(unsigned short, l1);
}

// -------- fill borders of h1p/h2p with 0x80 (biased zero) --------
__global__ void fill_k(unsigned char* __restrict__ h1p, unsigned char* __restrict__ h2p) {
  const int idx = blockIdx.x * 256 + threadIdx.x;
  const uint4 v = make_uint4(0x80808080u, 0x80808080u, 0x80808080u, 0x80808080u);
  if (idx < 66048) {
    const int q = idx & 3; const int u = idx >> 2;
    const int pxi = u % WP; const int rr = u / WP;
    const int bb = rr >> 2, sel = rr & 3;
    const int row = (sel < 2) ? sel : 512 + sel;
    *(uint4*)(h1p + (((size_t)bb * HP + row) * WP + pxi) * 64 + q * 16) = v;
  } else if (idx < 131584) {
    const int e = idx - 66048; const int q = e & 3; int u = e >> 2;
    const int c = u & 3; u >>= 2;
    const int row = 2 + (u & 511); const int bb = u >> 9;
    const int col = (c < 2) ? c : 512 + c;
    *(uint4*)(h1p + (((size_t)bb * HP + row) * WP + col) * 64 + q * 16) = v;
  } else if (idx < 164608) {
    const int e = idx - 131584; const int q = e & 1; const int u = e >> 1;
    const int pxi = u % WP; const int rr = u / WP;
    const int bb = rr >> 2, sel = rr & 3;
    const int row = (sel < 2) ? sel : 512 + sel;
    *(uint4*)(h2p + (((size_t)bb * HP + row) * WP + pxi) * 32 + q * 16) = v;
  } else {
    const int e = idx - 164608; const int q = e & 1; int u = e >> 1;
    const int c = u & 3; u >>= 2;
    const int row = 2 + (u & 511); const int bb = u >> 9;
    const int col = (c < 2) ? c : 512 + c;
    *(uint4*)(h2p + (((size_t)bb * HP + row) * WP + col) * 32 + q * 16) = v;
  }
}

// -------- conv1: f16-split MFMA, 4-row blocks (L1-resident window), 3-deep prefetch --
// block = 512 thr = 8 waves = 2 x-halves x 4 rows; 128 px x 4 rows per block.
// XCD k owns image k (planes L2-resident); per-block input window ~27 KB fits L1.
__global__ __launch_bounds__(512) void conv1_k(
    const unsigned short* __restrict__ planes,
    const unsigned short* __restrict__ w1frag,
    const float* __restrict__ qA,
    const float* __restrict__ b1q,
    unsigned char* __restrict__ h1p) {
  __shared__ alignas(16) unsigned short wf[18432];
  for (int i = threadIdx.x; i < 2304; i += 512)
    ((int4*)wf)[i] = ((const int4*)w1frag)[i];
  __syncthreads();

  // swizzle: 4096 blocks, XCD k = bid&7 owns image k (512 blocks/image)
  const int wg = (blockIdx.x & 7) * 512 + (blockIdx.x >> 3);
  const int b   = wg >> 9;
  const int rem = wg & 511;
  const int xt  = rem & 3;           // 128-px x-tile
  const int y0  = (rem >> 2) * 4;    // 4-row group
  const int l = threadIdx.x & 63;
  const int wv = threadIdx.x >> 6;
  const int wrow = wv & 3;
  const int y = y0 + wrow;
  const int pxw = xt * 128 + (wv >> 2) * 64;
  const int r = l & 15, kb = l >> 4;

  const unsigned short* pb = planes + (size_t)(r & 1) * (2 * PT)
                           + ((size_t)b * PROWS + y) * PCOLS + (pxw + (r & ~1));
  int offs[9];
  #pragma unroll
  for (int j = 0; j < 9; ++j) {
    const int t0 = j * 32 + kb * 8;
    const int term = (t0 >= 144) ? 1 : 0;
    const int rem2 = t0 - term * 144;
    offs[j] = term * (int)PT + (rem2 >> 4) * PCOLS + (rem2 & 8);
  }

  v4f acc[4][4];   // [p = px-tile][o = oc-tile]
  #pragma unroll
  for (int p = 0; p < 4; ++p)
    #pragma unroll
    for (int o = 0; o < 4; ++o) acc[p][o] = (v4f){0.f, 0.f, 0.f, 0.f};

  // 3-deep rotating prefetch: issue j+2's A-loads before j's MFMAs
  v8h av[3][4];
  #pragma unroll
  for (int jj = 0; jj < 2; ++jj) {
    #pragma unroll
    for (int p = 0; p < 4; ++p) {
      uint4 tv;
      __builtin_memcpy(&tv,
          __builtin_assume_aligned((const void*)(pb + offs[jj] + p * 16), 4), 16);
      av[jj][p] = __builtin_bit_cast(v8h, tv);
    }
  }
  #pragma unroll
  for (int j = 0; j < 9; ++j) {
    if (j < 7) {
      const int slot = (j + 2) % 3;
      #pragma unroll
      for (int p = 0; p < 4; ++p) {
        uint4 tv;
        __builtin_memcpy(&tv,
            __builtin_assume_aligned((const void*)(pb + offs[j + 2] + p * 16), 4), 16);
        av[slot][p] = __builtin_bit_cast(v8h, tv);
      }
    }
    const int cur = j % 3;
    #pragma unroll
    for (int o = 0; o < 4; ++o) {
      const v8h bw = *(const v8h*)(wf + ((size_t)(j * 4 + o) * 64 + l) * 8);
      #pragma unroll
      for (int p = 0; p < 4; ++p)
        acc[p][o] = __builtin_amdgcn_mfma_f32_16x16x32_f16(bw, av[cur][p], acc[p][o], 0, 0, 0);
    }
  }

  const float A1 = qA[0];
  unsigned int* ob = (unsigned int*)(h1p
      + (((size_t)b * HP + y + 2) * WP + 2 + pxw + r) * 64 + kb * 4);
  #pragma unroll
  for (int o = 0; o < 4; ++o) {
    const v4f bq = *(const v4f*)(b1q + o * 16 + kb * 4);
    #pragma unroll
    for (int p = 0; p < 4; ++p) {
      unsigned int dw = 0;
      #pragma unroll
      for (int reg = 0; reg < 4; ++reg) {
        const float t = acc[p][o][reg] * A1 + bq[reg];
        int qi = (int)rintf(t);
        qi = qi < -128 ? -128 : (qi > 127 ? 127 : qi);
        dw |= ((unsigned int)qi & 0xFFu) << (8 * reg);
      }
      ob[p * 256 + o * 4] = dw;
    }
  }
}

// -------- conv2: mfma_i32_32x32x32_i8, fma-folded quant epilogue ------
__global__ __launch_bounds__(256) void conv2_k(
    const unsigned char* __restrict__ h1p,
    const int4* __restrict__ w2s,
    const int* __restrict__ corrf,
    const float* __restrict__ qA,
    const float* __restrict__ b2q,
    unsigned char* __restrict__ h2p) {
  __shared__ alignas(16) signed char wlds[51200];
  __shared__ alignas(16) int clds[32];
  {
    int4* dst = (int4*)wlds;
    for (int i = threadIdx.x; i < 3200; i += 256) dst[i] = w2s[i];
    if (threadIdx.x < 32) clds[threadIdx.x] = corrf[threadIdx.x];
  }
  __syncthreads();

  const int l = threadIdx.x & 63;
  const int wv = threadIdx.x >> 6;
  const int pl = l & 31;          // pixel lane
  const int hi = l >> 5;          // k-chunk selector
  const int y = blockIdx.y * 16 + wv * 4;
  const int b = blockIdx.z;
  const int xw = blockIdx.x * 32;

  v16i acc[4];
  #pragma unroll
  for (int t = 0; t < 4; ++t)
    #pragma unroll
    for (int e = 0; e < 16; ++e) acc[t][e] = 0;

  const size_t rstride = (size_t)WP * 64;
  const unsigned char* abase = h1p + (((size_t)b * HP + y) * WP + xw + pl) * 64 + hi * 16;
  const signed char* wbase = wlds + l * 16;

  #pragma unroll
  for (int kx = 0; kx < 5; ++kx) {
    v4i a[8][2];
    #pragma unroll
    for (int row = 0; row < 8; ++row) {
      a[row][0] = *(const v4i*)(abase + kx * 64 + row * rstride);
      a[row][1] = *(const v4i*)(abase + kx * 64 + row * rstride + 32);
    }
    #pragma unroll
    for (int ky = 0; ky < 5; ++ky) {
      #pragma unroll
      for (int h = 0; h < 2; ++h) {
        const v4i wfr = *(const v4i*)(wbase + ((ky * 5 + kx) * 2 + h) * 1024);
        #pragma unroll
        for (int t = 0; t < 4; ++t)
          acc[t] = __builtin_amdgcn_mfma_i32_32x32x32_i8(wfr, a[ky + t][h], acc[t], 0, 0, 0);
      }
    }
  }

  const float A2 = qA[1];
  #pragma unroll
  for (int t = 0; t < 4; ++t) {
    unsigned char* ob = h2p + (((size_t)b * HP + y + t + 2) * WP + xw + 2 + pl) * 32 + hi * 4;
    #pragma unroll
    for (int g = 0; g < 4; ++g) {
      const int ocb = g * 8 + hi * 4;
      const v4f bq = *(const v4f*)(b2q + ocb);
      const v4i cv = *(const v4i*)(clds + ocb);
      unsigned int dw = 0;
      #pragma unroll
      for (int q = 0; q < 4; ++q) {
        const int tot = acc[t][g * 4 + q] + cv[q] * 128;
        const float v = (float)tot * A2 + bq[q];
        int qi = (int)rintf(v);
        qi = qi < -128 ? -128 : (qi > 127 ? 127 : qi);
        dw |= ((unsigned int)qi & 0xFFu) << (8 * q);
      }
      *(unsigned int*)(ob + g * 8) = dw;
    }
  }
}

// -------- conv3: NHWC, vectorized 16B row loads + static-indexed dot4 (exact) ------
__global__ __launch_bounds__(256) void conv3_k(
    const unsigned char* __restrict__ h2p,
    const signed char* __restrict__ w3p,
    const int* __restrict__ fs3,
    const float* __restrict__ b3,
    const float* __restrict__ scales,
    const float* __restrict__ s2, const float* __restrict__ s3,
    float* __restrict__ out) {
  const int p  = blockIdx.x * 256 + threadIdx.x;
  const int px = p & (WW - 1);
  const int py = (p >> 9) & (HH - 1);
  const int bz = p >> 18;

  const int* wq = (const int*)w3p;   // [tap][8 dwords]
  const unsigned char* base = h2p + (((size_t)bz * HP + py) * WP + px) * 32;

  int acc = 0;
  #pragma unroll
  for (int ky = 0; ky < 5; ++ky) {
    const v4i* rp = (const v4i*)(base + (size_t)ky * WP * 32);
    v4i c[10];
    #pragma unroll
    for (int g = 0; g < 10; ++g) c[g] = rp[g];
    const int* wrow = wq + ky * 40;
    #pragma unroll
    for (int kx = 0; kx < 5; ++kx) {
      #pragma unroll
      for (int g = 0; g < 8; ++g) {
        const int idx = kx * 8 + g;
        acc = DOT4(c[idx >> 2][idx & 3], wrow[idx], acc);
      }
    }
  }

  const int tot = acc + fs3[0] * 128;
  const float step2 = s2[0] / 255.0f;
  const float sc3 = s3[0], step3 = sc3 / 255.0f;
  const float y = (float)tot * (step2 * scales[2]) + b3[0];
  const float c = fminf(fmaxf(y, 0.0f), sc3);
  float q = rintf(c / step3);
  q = fminf(fmaxf(q, 0.0f), 255.0f);
  out[p] = q * step3;
}

extern "C" void kernel_launch(void* const* d_in, const int* in_sizes, int n_in,
                              void* d_out, int out_size, void* d_ws, size_t ws_size,
                              hipStream_t stream) {
  const float* x  = (const float*)d_in[0];
  const float* w1 = (const float*)d_in[1];
  const float* b1 = (const float*)d_in[2];
  const float* w2 = (const float*)d_in[3];
  const float* b2 = (const float*)d_in[4];
  const float* w3 = (const float*)d_in[5];
  const float* b3 = (const float*)d_in[6];
  const float* s1 = (const float*)d_in[7];
  const float* s2 = (const float*)d_in[8];
  const float* s3 = (const float*)d_in[9];

  if (ws_size < WS_NEED) return;

  char* ws = (char*)d_ws;
  float*          scales  = (float*)(ws + SCALES_OFF);
  int*            corrf   = (int*)(ws + CORRF_OFF);
  float*          qA      = (float*)(ws + QA_OFF);
  int*            fs3     = (int*)(ws + FS3_OFF);
  float*          qw1     = (float*)(ws + QW1_OFF);
  float*          b1q     = (float*)(ws + B1Q_OFF);
  float*          b2q     = (float*)(ws + B2Q_OFF);
  unsigned short* w1frag  = (unsigned short*)(ws + W1FRAG_OFF);
  signed char*    w2s     = (signed char*)(ws + W2S_OFF);
  signed char*    w3p     = (signed char*)(ws + W3P_OFF);
  unsigned char*  h1p     = (unsigned char*)(ws + H1_OFF);
  unsigned char*  h2p     = (unsigned char*)(ws + H2_OFF);
  unsigned short* planes  = (unsigned short*)(ws + H2_OFF);  // overlaps h2p until conv2

  quant_weights_k<<<3, 256, 0, stream>>>(w1, w2, w3, scales, qw1, w2s, w3p);
  prep_k<<<1, 256, 0, stream>>>(w2s, w3p, qw1, b1, b2, s1, s2, scales,
                                corrf, fs3, w1frag, qA, b1q, b2q);
  prep_x_k<<<(int)(PT / 256), 256, 0, stream>>>(x, planes);

  conv1_k<<<BB * HH, 512, 0, stream>>>(planes, w1frag, qA, b1q, h1p);
  fill_k<<<771, 256, 0, stream>>>(h1p, h2p);   // after conv1 (h2p region held planes)

  dim3 g2(16, 32, BB);
  conv2_k<<<g2, 256, 0, stream>>>(h1p, (const int4*)w2s, corrf, qA, b2q, h2p);

  const int npix = BB * HH * WW;
  conv3_k<<<npix / 256, 256, 0, stream>>>(h2p, w3p, fs3, b3, scales, s2, s3, (float*)d_out);
}